// Round 9
// baseline (264.481 us; speedup 1.0000x reference)
//
#include <hip/hip_runtime.h>
#include <math.h>

#define BB 4
#define NWIRE 1536
#define NFEAT 16
#define BS 256
#define NBLK 256         // blocks for A1/A2 binning passes
#define DSHIFT 9         // 512 dsts per coarse bucket
#define DPB (1 << DSHIFT)
#define MAXNB 1024       // max buckets: supports n <= 524288 (src packed in 19 bits)

// ---- K1: per-wire scalar precompute ---------------------------------------
__global__ void k_wires(const float* __restrict__ fw, const float* __restrict__ sw,
                        const float* __restrict__ W, const float* __restrict__ att_src,
                        const float* __restrict__ att_dst, const float* __restrict__ wmlp,
                        float4* __restrict__ fwpre, float4* __restrict__ swpre) {
    int t = blockIdx.x * blockDim.x + threadIdx.x;
    if (t >= BB * NWIRE) return;
    const float* fp = fw + (size_t)t * NFEAT;
    const float* sp = sw + (size_t)t * NFEAT;
    float hf[4] = {0, 0, 0, 0}, hs[4] = {0, 0, 0, 0};
    #pragma unroll
    for (int k = 0; k < NFEAT; ++k) {
        float a = fp[k], b = sp[k];
        #pragma unroll
        for (int c = 0; c < 4; ++c) {
            hf[c] = fmaf(a, W[k * 4 + c], hf[c]);
            hs[c] = fmaf(b, W[(NFEAT + k) * 4 + c], hs[c]);
        }
    }
    float fs = 0, fd = 0, fq = 0, ss = 0, sd = 0, sq = 0;
    #pragma unroll
    for (int c = 0; c < 4; ++c) {
        float as = att_src[c], ad = att_dst[c], wm = wmlp[c];
        fs = fmaf(hf[c], as, fs); fd = fmaf(hf[c], ad, fd); fq = fmaf(hf[c], wm, fq);
        ss = fmaf(hs[c], as, ss); sd = fmaf(hs[c], ad, sd); sq = fmaf(hs[c], wm, sq);
    }
    fwpre[t] = make_float4(fs, fd, fq, 0.0f);
    swpre[t] = make_float4(ss, sd, sq, 0.0f);
}

// ---- K2: per-node scalars: srcdat4[2i]=ps[4], srcdat4[2i+1]=q[4], dstdat4[i]=pd[4]
__global__ void k_nodes(const int* __restrict__ indices, const float* __restrict__ crossings,
                        const float* __restrict__ bbox, const float* __restrict__ W,
                        const float* __restrict__ att_src, const float* __restrict__ att_dst,
                        const float* __restrict__ wmlp,
                        const float4* __restrict__ fwpre, const float4* __restrict__ swpre,
                        float4* __restrict__ srcdat4, float4* __restrict__ dstdat4, int n) {
    int i = blockIdx.x * blockDim.x + threadIdx.x;
    if (i >= n) return;
    float inv = rsqrtf(bbox[0] * bbox[0] + bbox[1] * bbox[1] + bbox[2] * bbox[2]);
    int i0 = indices[2 * i], i1 = indices[2 * i + 1];
    float x0 = crossings[2 * i] * inv, x1 = crossings[2 * i + 1] * inv;
    float xs = 0, xd = 0, xq = 0;
    #pragma unroll
    for (int c = 0; c < 4; ++c) {
        float hc = fmaf(x0, W[32 * 4 + c], x1 * W[33 * 4 + c]);
        xs = fmaf(hc, att_src[c], xs);
        xd = fmaf(hc, att_dst[c], xd);
        xq = fmaf(hc, wmlp[c], xq);
    }
    float4 f0 = fwpre[0 * NWIRE + i0], s0 = swpre[0 * NWIRE + i1];
    float4 f1 = fwpre[1 * NWIRE + i0], s1 = swpre[1 * NWIRE + i1];
    float4 f2 = fwpre[2 * NWIRE + i0], s2 = swpre[2 * NWIRE + i1];
    float4 f3 = fwpre[3 * NWIRE + i0], s3 = swpre[3 * NWIRE + i1];
    srcdat4[(size_t)i * 2] = make_float4(f0.x + s0.x + xs, f1.x + s1.x + xs,
                                         f2.x + s2.x + xs, f3.x + s3.x + xs);
    srcdat4[(size_t)i * 2 + 1] = make_float4(f0.z + s0.z + xq, f1.z + s1.z + xq,
                                             f2.z + s2.z + xq, f3.z + s3.z + xq);
    dstdat4[i] = make_float4(f0.y + s0.y + xd, f1.y + s1.y + xd,
                             f2.y + s2.y + xd, f3.y + s3.y + xd);
}

// ---- A1: per-block coarse-bucket histogram (LDS only) ----------------------
__global__ void k_binA1(const int* __restrict__ ei, int ne, int nb, int chunk,
                        int* __restrict__ bh) {
    __shared__ int lc[MAXNB];
    for (int i = threadIdx.x; i < nb; i += BS) lc[i] = 0;
    __syncthreads();
    int blk = blockIdx.x;
    int e0 = blk * chunk, e1 = min(e0 + chunk, ne);
    const int* dstp = ei + ne;
    for (int e = e0 + threadIdx.x; e < e1; e += BS)
        atomicAdd(&lc[dstp[e] >> DSHIFT], 1);
    __syncthreads();
    for (int b = threadIdx.x; b < nb; b += BS)
        bh[b * NBLK + blk] = lc[b];
}

// ---- S1: per-bucket exclusive scan over blocks (in place) + bucket totals --
__global__ void k_scanBlk(int* __restrict__ bh, int* __restrict__ btot, int nb) {
    int b = blockIdx.x * blockDim.x + threadIdx.x;
    if (b >= nb) return;
    int4* p = (int4*)(bh + (size_t)b * NBLK);
    int run = 0;
    #pragma unroll 4
    for (int k = 0; k < NBLK / 4; ++k) {
        int4 v = p[k];
        int4 o;
        o.x = run; run += v.x;
        o.y = run; run += v.y;
        o.z = run; run += v.z;
        o.w = run; run += v.w;
        p[k] = o;
    }
    btot[b] = run;
}

// ---- S2: exclusive scan of bucket totals -> bbase (+ sentinel) -------------
__global__ void k_scanBuck(const int* __restrict__ btot, int* __restrict__ bbase,
                           int nb, int ne) {
    __shared__ int sh[MAXNB];
    int t = threadIdx.x;  // blockDim == MAXNB
    int v = (t < nb) ? btot[t] : 0;
    sh[t] = v;
    __syncthreads();
    for (int ofs = 1; ofs < MAXNB; ofs <<= 1) {
        int u = (t >= ofs) ? sh[t - ofs] : 0;
        __syncthreads();
        sh[t] += u;
        __syncthreads();
    }
    if (t < nb) bbase[t] = sh[t] - v;
    if (t == 0) bbase[nb] = ne;
}

// ---- A2: compute a_e, place records in (block,bucket) private sub-ranges ---
// record: x = (d & (DPB-1)) << 19 | src,  y = float bits of a_e
__global__ void k_binA2(const int* __restrict__ ei, const float* __restrict__ eattr,
                        const float* __restrict__ We, const float* __restrict__ att_edge,
                        const int* __restrict__ bh, const int* __restrict__ bbase,
                        int ne, int nb, int chunk, int2* __restrict__ recs) {
    __shared__ int curs[MAXNB];
    int blk = blockIdx.x;
    for (int b = threadIdx.x; b < nb; b += BS)
        curs[b] = bbase[b] + bh[b * NBLK + blk];
    __syncthreads();
    float v0 = fmaf(We[0], att_edge[0], fmaf(We[1], att_edge[1], fmaf(We[2], att_edge[2], We[3] * att_edge[3])));
    float v1 = fmaf(We[4], att_edge[0], fmaf(We[5], att_edge[1], fmaf(We[6], att_edge[2], We[7] * att_edge[3])));
    float v2 = fmaf(We[8], att_edge[0], fmaf(We[9], att_edge[1], fmaf(We[10], att_edge[2], We[11] * att_edge[3])));
    float v3 = fmaf(We[12], att_edge[0], fmaf(We[13], att_edge[1], fmaf(We[14], att_edge[2], We[15] * att_edge[3])));
    const int* srcp = ei;
    const int* dstp = ei + ne;
    int e0 = blk * chunk, e1 = min(e0 + chunk, ne);
    for (int e = e0 + threadIdx.x; e < e1; e += BS) {
        int s = srcp[e], d = dstp[e];
        const float4 ea = *(const float4*)(eattr + (size_t)e * 4);
        float ae = fmaf(ea.x, v0, fmaf(ea.y, v1, fmaf(ea.z, v2, ea.w * v3)));
        int b = d >> DSHIFT;
        int pos = atomicAdd(&curs[b], 1);
        recs[pos] = make_int2(((d & (DPB - 1)) << 19) | s, __float_as_int(ae));
    }
}

// ---- GB: fused per-bucket GAT — LDS accumulators, record-parallel ----------
__global__ void k_gatB(const int2* __restrict__ recs, const int* __restrict__ bbase,
                       const float4* __restrict__ srcdat4, const float4* __restrict__ dstdat4,
                       const float* __restrict__ bias, const float* __restrict__ wmlp,
                       const float* __restrict__ bmlp, float* __restrict__ out, int n) {
    __shared__ float acc[DPB * 8];  // per dst: d0,n0,d1,n1,d2,n2,d3,n3
    __shared__ float pds[DPB * 4];
    int b = blockIdx.x;
    int r0 = bbase[b], r1 = bbase[b + 1];
    int dbase = b << DSHIFT;
    int dmax = min(DPB, n - dbase);
    for (int i = threadIdx.x; i < DPB * 8; i += BS) acc[i] = 0.0f;
    for (int i = threadIdx.x; i < dmax; i += BS) {
        float4 pd = dstdat4[dbase + i];
        pds[i * 4]     = pd.x;
        pds[i * 4 + 1] = pd.y;
        pds[i * 4 + 2] = pd.z;
        pds[i * 4 + 3] = pd.w;
    }
    __syncthreads();
    for (int i = r0 + threadIdx.x; i < r1; i += BS) {
        int2 r = recs[i];
        int dlo = (unsigned)r.x >> 19;
        int src = r.x & 0x7FFFF;
        float ae = __int_as_float(r.y);
        float4 ps = srcdat4[(size_t)src * 2];
        float4 q  = srcdat4[(size_t)src * 2 + 1];
        float lg, ex;
        lg = ps.x + pds[dlo * 4]     + ae; lg = lg > 0.0f ? lg : 0.2f * lg; ex = expf(lg);
        atomicAdd(&acc[dlo * 8],     ex); atomicAdd(&acc[dlo * 8 + 1], ex * q.x);
        lg = ps.y + pds[dlo * 4 + 1] + ae; lg = lg > 0.0f ? lg : 0.2f * lg; ex = expf(lg);
        atomicAdd(&acc[dlo * 8 + 2], ex); atomicAdd(&acc[dlo * 8 + 3], ex * q.y);
        lg = ps.z + pds[dlo * 4 + 2] + ae; lg = lg > 0.0f ? lg : 0.2f * lg; ex = expf(lg);
        atomicAdd(&acc[dlo * 8 + 4], ex); atomicAdd(&acc[dlo * 8 + 5], ex * q.z);
        lg = ps.w + pds[dlo * 4 + 3] + ae; lg = lg > 0.0f ? lg : 0.2f * lg; ex = expf(lg);
        atomicAdd(&acc[dlo * 8 + 6], ex); atomicAdd(&acc[dlo * 8 + 7], ex * q.w);
    }
    __syncthreads();
    float cst = fmaf(bias[0], wmlp[0], fmaf(bias[1], wmlp[1], fmaf(bias[2], wmlp[2], bias[3] * wmlp[3]))) + bmlp[0];
    for (int i = threadIdx.x; i < dmax; i += BS) {
        int d = dbase + i;
        out[d]                 = acc[i * 8 + 1] / (acc[i * 8]     + 1e-16f) + cst;
        out[(size_t)n + d]     = acc[i * 8 + 3] / (acc[i * 8 + 2] + 1e-16f) + cst;
        out[(size_t)2 * n + d] = acc[i * 8 + 5] / (acc[i * 8 + 4] + 1e-16f) + cst;
        out[(size_t)3 * n + d] = acc[i * 8 + 7] / (acc[i * 8 + 6] + 1e-16f) + cst;
    }
}

extern "C" void kernel_launch(void* const* d_in, const int* in_sizes, int n_in,
                              void* d_out, int out_size, void* d_ws, size_t ws_size,
                              hipStream_t stream) {
    const float* first_wires  = (const float*)d_in[0];
    const float* second_wires = (const float*)d_in[1];
    const float* crossings    = (const float*)d_in[2];
    const float* bbox         = (const float*)d_in[3];
    const float* edge_attr    = (const float*)d_in[4];
    const int*   indices      = (const int*)d_in[5];
    const int*   edge_index   = (const int*)d_in[6];
    const float* W            = (const float*)d_in[7];
    const float* att_src      = (const float*)d_in[8];
    const float* att_dst      = (const float*)d_in[9];
    const float* W_e          = (const float*)d_in[10];
    const float* att_edge     = (const float*)d_in[11];
    const float* bias         = (const float*)d_in[12];
    const float* w_mlp        = (const float*)d_in[13];
    const float* b_mlp        = (const float*)d_in[14];
    float* out = (float*)d_out;

    const int n  = in_sizes[5] / 2;   // N_CROSS (must be < 524288 for packing)
    const int ne = in_sizes[6] / 2;   // N_EDGES
    const int nb = (n + DPB - 1) >> DSHIFT;
    const int chunk = (ne + NBLK - 1) / NBLK;

    // workspace layout (16B-aligned blocks)
    char* ws = (char*)d_ws;
    size_t off = 0;
    float4* fwpre   = (float4*)(ws + off); off += (size_t)BB * NWIRE * 16;
    float4* swpre   = (float4*)(ws + off); off += (size_t)BB * NWIRE * 16;
    float4* srcdat4 = (float4*)(ws + off); off += (size_t)n * 32;
    float4* dstdat4 = (float4*)(ws + off); off += (size_t)n * 16;
    int*    bh      = (int*)(ws + off);    off += (size_t)nb * NBLK * 4;
    int*    btot    = (int*)(ws + off);    off += ((size_t)nb * 4 + 15) & ~15ull;
    int*    bbase   = (int*)(ws + off);    off += ((size_t)(nb + 1) * 4 + 15) & ~15ull;
    int2*   recs    = (int2*)(ws + off);   off += (size_t)ne * 8;

    hipLaunchKernelGGL(k_wires, dim3((BB * NWIRE + BS - 1) / BS), dim3(BS), 0, stream,
                       first_wires, second_wires, W, att_src, att_dst, w_mlp, fwpre, swpre);
    hipLaunchKernelGGL(k_nodes, dim3((n + BS - 1) / BS), dim3(BS), 0, stream,
                       indices, crossings, bbox, W, att_src, att_dst, w_mlp,
                       fwpre, swpre, srcdat4, dstdat4, n);
    hipLaunchKernelGGL(k_binA1, dim3(NBLK), dim3(BS), 0, stream,
                       edge_index, ne, nb, chunk, bh);
    hipLaunchKernelGGL(k_scanBlk, dim3((nb + 63) / 64), dim3(64), 0, stream,
                       bh, btot, nb);
    hipLaunchKernelGGL(k_scanBuck, dim3(1), dim3(MAXNB), 0, stream,
                       btot, bbase, nb, ne);
    hipLaunchKernelGGL(k_binA2, dim3(NBLK), dim3(BS), 0, stream,
                       edge_index, edge_attr, W_e, att_edge, bh, bbase, ne, nb, chunk, recs);
    hipLaunchKernelGGL(k_gatB, dim3(nb), dim3(BS), 0, stream,
                       recs, bbase, srcdat4, dstdat4, bias, w_mlp, b_mlp, out, n);
}

// Round 10
// 257.921 us; speedup vs baseline: 1.0254x; 1.0254x over previous
//
#include <hip/hip_runtime.h>
#include <math.h>

#define BB 4
#define NWIRE 1536
#define NFEAT 16
#define BS 256
#define NBLK 256         // blocks for A1/A2 binning passes
#define DSHIFT 8         // 256 dsts per coarse bucket
#define DPB (1 << DSHIFT)
#define MAXNB 2048       // max buckets: supports n <= 524288 (src packed in 19 bits)

// ---- K1: per-wire scalar precompute ---------------------------------------
__global__ void k_wires(const float* __restrict__ fw, const float* __restrict__ sw,
                        const float* __restrict__ W, const float* __restrict__ att_src,
                        const float* __restrict__ att_dst, const float* __restrict__ wmlp,
                        float4* __restrict__ fwpre, float4* __restrict__ swpre) {
    int t = blockIdx.x * blockDim.x + threadIdx.x;
    if (t >= BB * NWIRE) return;
    const float* fp = fw + (size_t)t * NFEAT;
    const float* sp = sw + (size_t)t * NFEAT;
    float hf[4] = {0, 0, 0, 0}, hs[4] = {0, 0, 0, 0};
    #pragma unroll
    for (int k = 0; k < NFEAT; ++k) {
        float a = fp[k], b = sp[k];
        #pragma unroll
        for (int c = 0; c < 4; ++c) {
            hf[c] = fmaf(a, W[k * 4 + c], hf[c]);
            hs[c] = fmaf(b, W[(NFEAT + k) * 4 + c], hs[c]);
        }
    }
    float fs = 0, fd = 0, fq = 0, ss = 0, sd = 0, sq = 0;
    #pragma unroll
    for (int c = 0; c < 4; ++c) {
        float as = att_src[c], ad = att_dst[c], wm = wmlp[c];
        fs = fmaf(hf[c], as, fs); fd = fmaf(hf[c], ad, fd); fq = fmaf(hf[c], wm, fq);
        ss = fmaf(hs[c], as, ss); sd = fmaf(hs[c], ad, sd); sq = fmaf(hs[c], wm, sq);
    }
    fwpre[t] = make_float4(fs, fd, fq, 0.0f);
    swpre[t] = make_float4(ss, sd, sq, 0.0f);
}

// ---- K2: per-node scalars: srcdat4[2i]=ps[4], srcdat4[2i+1]=q[4], dstdat4[i]=pd[4]
__global__ void k_nodes(const int* __restrict__ indices, const float* __restrict__ crossings,
                        const float* __restrict__ bbox, const float* __restrict__ W,
                        const float* __restrict__ att_src, const float* __restrict__ att_dst,
                        const float* __restrict__ wmlp,
                        const float4* __restrict__ fwpre, const float4* __restrict__ swpre,
                        float4* __restrict__ srcdat4, float4* __restrict__ dstdat4, int n) {
    int i = blockIdx.x * blockDim.x + threadIdx.x;
    if (i >= n) return;
    float inv = rsqrtf(bbox[0] * bbox[0] + bbox[1] * bbox[1] + bbox[2] * bbox[2]);
    int2 idx = ((const int2*)indices)[i];
    float2 xc = ((const float2*)crossings)[i];
    int i0 = idx.x, i1 = idx.y;
    float x0 = xc.x * inv, x1 = xc.y * inv;
    float xs = 0, xd = 0, xq = 0;
    #pragma unroll
    for (int c = 0; c < 4; ++c) {
        float hc = fmaf(x0, W[32 * 4 + c], x1 * W[33 * 4 + c]);
        xs = fmaf(hc, att_src[c], xs);
        xd = fmaf(hc, att_dst[c], xd);
        xq = fmaf(hc, wmlp[c], xq);
    }
    float4 f0 = fwpre[0 * NWIRE + i0], s0 = swpre[0 * NWIRE + i1];
    float4 f1 = fwpre[1 * NWIRE + i0], s1 = swpre[1 * NWIRE + i1];
    float4 f2 = fwpre[2 * NWIRE + i0], s2 = swpre[2 * NWIRE + i1];
    float4 f3 = fwpre[3 * NWIRE + i0], s3 = swpre[3 * NWIRE + i1];
    srcdat4[(size_t)i * 2] = make_float4(f0.x + s0.x + xs, f1.x + s1.x + xs,
                                         f2.x + s2.x + xs, f3.x + s3.x + xs);
    srcdat4[(size_t)i * 2 + 1] = make_float4(f0.z + s0.z + xq, f1.z + s1.z + xq,
                                             f2.z + s2.z + xq, f3.z + s3.z + xq);
    dstdat4[i] = make_float4(f0.y + s0.y + xd, f1.y + s1.y + xd,
                             f2.y + s2.y + xd, f3.y + s3.y + xd);
}

// ---- A1: per-block coarse-bucket histogram (LDS only) ----------------------
// bh layout: [block][bucket] (row-contiguous per block)
__global__ void k_binA1(const int* __restrict__ ei, int ne, int nb, int chunk,
                        int* __restrict__ bh) {
    __shared__ int lc[MAXNB];
    for (int i = threadIdx.x; i < nb; i += BS) lc[i] = 0;
    __syncthreads();
    int blk = blockIdx.x;
    const int* dstp = ei + ne;
    int e0 = blk * chunk, e1 = min(e0 + chunk, ne);
    int e = e0 + threadIdx.x * 4;
    for (; e + 3 < e1; e += BS * 4) {
        int4 d4 = *(const int4*)(dstp + e);
        atomicAdd(&lc[d4.x >> DSHIFT], 1);
        atomicAdd(&lc[d4.y >> DSHIFT], 1);
        atomicAdd(&lc[d4.z >> DSHIFT], 1);
        atomicAdd(&lc[d4.w >> DSHIFT], 1);
    }
    for (; e < e1; e += BS * 4) {
        int ke = min(e + 4, e1);
        for (int k = e; k < ke; ++k) atomicAdd(&lc[dstp[k] >> DSHIFT], 1);
    }
    __syncthreads();
    int* row = bh + (size_t)blk * nb;
    for (int b = threadIdx.x; b < nb; b += BS) row[b] = lc[b];
}

// ---- S1: per-bucket exclusive scan over blocks (coalesced, 8-deep loads) ---
__global__ void k_scanBlk(int* __restrict__ bh, int* __restrict__ btot, int nb) {
    int b = blockIdx.x * blockDim.x + threadIdx.x;
    if (b >= nb) return;
    int run = 0;
    for (int k0 = 0; k0 < NBLK; k0 += 8) {
        int v[8];
        #pragma unroll
        for (int j = 0; j < 8; ++j) v[j] = bh[(size_t)(k0 + j) * nb + b];
        #pragma unroll
        for (int j = 0; j < 8; ++j) {
            int t = v[j];
            bh[(size_t)(k0 + j) * nb + b] = run;
            run += t;
        }
    }
    btot[b] = run;
}

// ---- S2: exclusive scan of bucket totals (1024 thr x 2 elems) --------------
__global__ void k_scanBuck(const int* __restrict__ btot, int* __restrict__ bbase,
                           int nb, int ne) {
    __shared__ int sh[1024];
    int t = threadIdx.x;
    int i0 = 2 * t, i1 = 2 * t + 1;
    int a = (i0 < nb) ? btot[i0] : 0;
    int b = (i1 < nb) ? btot[i1] : 0;
    sh[t] = a + b;
    __syncthreads();
    for (int ofs = 1; ofs < 1024; ofs <<= 1) {
        int u = (t >= ofs) ? sh[t - ofs] : 0;
        __syncthreads();
        sh[t] += u;
        __syncthreads();
    }
    int excl = sh[t] - (a + b);
    if (i0 < nb) bbase[i0] = excl;
    if (i1 < nb) bbase[i1] = excl + a;
    if (t == 0) bbase[nb] = ne;
}

// ---- A2: compute a_e, place records in (block,bucket) private sub-ranges ---
// record: x = (d & (DPB-1)) << 19 | src,  y = float bits of a_e
__global__ void k_binA2(const int* __restrict__ ei, const float* __restrict__ eattr,
                        const float* __restrict__ We, const float* __restrict__ att_edge,
                        const int* __restrict__ bh, const int* __restrict__ bbase,
                        int ne, int nb, int chunk, int2* __restrict__ recs) {
    __shared__ int curs[MAXNB];
    int blk = blockIdx.x;
    const int* row = bh + (size_t)blk * nb;
    for (int b = threadIdx.x; b < nb; b += BS)
        curs[b] = bbase[b] + row[b];
    __syncthreads();
    float v0 = fmaf(We[0], att_edge[0], fmaf(We[1], att_edge[1], fmaf(We[2], att_edge[2], We[3] * att_edge[3])));
    float v1 = fmaf(We[4], att_edge[0], fmaf(We[5], att_edge[1], fmaf(We[6], att_edge[2], We[7] * att_edge[3])));
    float v2 = fmaf(We[8], att_edge[0], fmaf(We[9], att_edge[1], fmaf(We[10], att_edge[2], We[11] * att_edge[3])));
    float v3 = fmaf(We[12], att_edge[0], fmaf(We[13], att_edge[1], fmaf(We[14], att_edge[2], We[15] * att_edge[3])));
    const int* srcp = ei;
    const int* dstp = ei + ne;
    const float4* ea4 = (const float4*)eattr;
    int e0 = blk * chunk, e1 = min(e0 + chunk, ne);
    int e = e0 + threadIdx.x * 4;
    for (; e + 3 < e1; e += BS * 4) {
        int4 s4 = *(const int4*)(srcp + e);
        int4 d4 = *(const int4*)(dstp + e);
        float4 a0 = ea4[e], a1 = ea4[e + 1], a2 = ea4[e + 2], a3 = ea4[e + 3];
        float ae0 = fmaf(a0.x, v0, fmaf(a0.y, v1, fmaf(a0.z, v2, a0.w * v3)));
        float ae1 = fmaf(a1.x, v0, fmaf(a1.y, v1, fmaf(a1.z, v2, a1.w * v3)));
        float ae2 = fmaf(a2.x, v0, fmaf(a2.y, v1, fmaf(a2.z, v2, a2.w * v3)));
        float ae3 = fmaf(a3.x, v0, fmaf(a3.y, v1, fmaf(a3.z, v2, a3.w * v3)));
        int p0 = atomicAdd(&curs[d4.x >> DSHIFT], 1);
        int p1 = atomicAdd(&curs[d4.y >> DSHIFT], 1);
        int p2 = atomicAdd(&curs[d4.z >> DSHIFT], 1);
        int p3 = atomicAdd(&curs[d4.w >> DSHIFT], 1);
        recs[p0] = make_int2(((d4.x & (DPB - 1)) << 19) | s4.x, __float_as_int(ae0));
        recs[p1] = make_int2(((d4.y & (DPB - 1)) << 19) | s4.y, __float_as_int(ae1));
        recs[p2] = make_int2(((d4.z & (DPB - 1)) << 19) | s4.z, __float_as_int(ae2));
        recs[p3] = make_int2(((d4.w & (DPB - 1)) << 19) | s4.w, __float_as_int(ae3));
    }
    for (; e < e1; e += BS * 4) {
        int ke = min(e + 4, e1);
        for (int k = e; k < ke; ++k) {
            int s = srcp[k], d = dstp[k];
            float4 ea = ea4[k];
            float ae = fmaf(ea.x, v0, fmaf(ea.y, v1, fmaf(ea.z, v2, ea.w * v3)));
            int pos = atomicAdd(&curs[d >> DSHIFT], 1);
            recs[pos] = make_int2(((d & (DPB - 1)) << 19) | s, __float_as_int(ae));
        }
    }
}

// ---- GB: fused per-bucket GAT — LDS accumulators, 4-deep record batching ---
__device__ __forceinline__ void gat_proc(int2 r, float4 ps, float4 q,
                                         float* acc, const float* pds) {
    int dlo = (unsigned)r.x >> 19;
    float ae = __int_as_float(r.y);
    float lg, ex;
    lg = ps.x + pds[dlo * 4]     + ae; lg = lg > 0.0f ? lg : 0.2f * lg; ex = expf(lg);
    atomicAdd(&acc[dlo * 8],     ex); atomicAdd(&acc[dlo * 8 + 1], ex * q.x);
    lg = ps.y + pds[dlo * 4 + 1] + ae; lg = lg > 0.0f ? lg : 0.2f * lg; ex = expf(lg);
    atomicAdd(&acc[dlo * 8 + 2], ex); atomicAdd(&acc[dlo * 8 + 3], ex * q.y);
    lg = ps.z + pds[dlo * 4 + 2] + ae; lg = lg > 0.0f ? lg : 0.2f * lg; ex = expf(lg);
    atomicAdd(&acc[dlo * 8 + 4], ex); atomicAdd(&acc[dlo * 8 + 5], ex * q.z);
    lg = ps.w + pds[dlo * 4 + 3] + ae; lg = lg > 0.0f ? lg : 0.2f * lg; ex = expf(lg);
    atomicAdd(&acc[dlo * 8 + 6], ex); atomicAdd(&acc[dlo * 8 + 7], ex * q.w);
}

__global__ void __launch_bounds__(BS)
k_gatB(const int2* __restrict__ recs, const int* __restrict__ bbase,
       const float4* __restrict__ srcdat4, const float4* __restrict__ dstdat4,
       const float* __restrict__ bias, const float* __restrict__ wmlp,
       const float* __restrict__ bmlp, float* __restrict__ out, int n) {
    __shared__ float acc[DPB * 8];  // per dst: d0,n0,d1,n1,d2,n2,d3,n3
    __shared__ float pds[DPB * 4];
    int b = blockIdx.x;
    int r0 = bbase[b], r1 = bbase[b + 1];
    int dbase = b << DSHIFT;
    int dmax = min(DPB, n - dbase);
    for (int i = threadIdx.x; i < DPB * 8; i += BS) acc[i] = 0.0f;
    for (int i = threadIdx.x; i < dmax; i += BS) {
        float4 pd = dstdat4[dbase + i];
        pds[i * 4]     = pd.x;
        pds[i * 4 + 1] = pd.y;
        pds[i * 4 + 2] = pd.z;
        pds[i * 4 + 3] = pd.w;
    }
    __syncthreads();
    int i = r0 + threadIdx.x;
    for (; i + 3 * BS < r1; i += 4 * BS) {
        int2 ra = recs[i], rb = recs[i + BS], rc = recs[i + 2 * BS], rd = recs[i + 3 * BS];
        int sa = ra.x & 0x7FFFF, sb = rb.x & 0x7FFFF;
        int sc = rc.x & 0x7FFFF, sd = rd.x & 0x7FFFF;
        float4 Pa = srcdat4[(size_t)sa * 2], Qa = srcdat4[(size_t)sa * 2 + 1];
        float4 Pb = srcdat4[(size_t)sb * 2], Qb = srcdat4[(size_t)sb * 2 + 1];
        float4 Pc = srcdat4[(size_t)sc * 2], Qc = srcdat4[(size_t)sc * 2 + 1];
        float4 Pd = srcdat4[(size_t)sd * 2], Qd = srcdat4[(size_t)sd * 2 + 1];
        gat_proc(ra, Pa, Qa, acc, pds);
        gat_proc(rb, Pb, Qb, acc, pds);
        gat_proc(rc, Pc, Qc, acc, pds);
        gat_proc(rd, Pd, Qd, acc, pds);
    }
    for (; i < r1; i += BS) {
        int2 r = recs[i];
        int s = r.x & 0x7FFFF;
        gat_proc(r, srcdat4[(size_t)s * 2], srcdat4[(size_t)s * 2 + 1], acc, pds);
    }
    __syncthreads();
    float cst = fmaf(bias[0], wmlp[0], fmaf(bias[1], wmlp[1], fmaf(bias[2], wmlp[2], bias[3] * wmlp[3]))) + bmlp[0];
    for (int i2 = threadIdx.x; i2 < dmax; i2 += BS) {
        int d = dbase + i2;
        out[d]                 = acc[i2 * 8 + 1] / (acc[i2 * 8]     + 1e-16f) + cst;
        out[(size_t)n + d]     = acc[i2 * 8 + 3] / (acc[i2 * 8 + 2] + 1e-16f) + cst;
        out[(size_t)2 * n + d] = acc[i2 * 8 + 5] / (acc[i2 * 8 + 4] + 1e-16f) + cst;
        out[(size_t)3 * n + d] = acc[i2 * 8 + 7] / (acc[i2 * 8 + 6] + 1e-16f) + cst;
    }
}

extern "C" void kernel_launch(void* const* d_in, const int* in_sizes, int n_in,
                              void* d_out, int out_size, void* d_ws, size_t ws_size,
                              hipStream_t stream) {
    const float* first_wires  = (const float*)d_in[0];
    const float* second_wires = (const float*)d_in[1];
    const float* crossings    = (const float*)d_in[2];
    const float* bbox         = (const float*)d_in[3];
    const float* edge_attr    = (const float*)d_in[4];
    const int*   indices      = (const int*)d_in[5];
    const int*   edge_index   = (const int*)d_in[6];
    const float* W            = (const float*)d_in[7];
    const float* att_src      = (const float*)d_in[8];
    const float* att_dst      = (const float*)d_in[9];
    const float* W_e          = (const float*)d_in[10];
    const float* att_edge     = (const float*)d_in[11];
    const float* bias         = (const float*)d_in[12];
    const float* w_mlp        = (const float*)d_in[13];
    const float* b_mlp        = (const float*)d_in[14];
    float* out = (float*)d_out;

    const int n  = in_sizes[5] / 2;   // N_CROSS (must be < 524288 for packing)
    const int ne = in_sizes[6] / 2;   // N_EDGES
    const int nb = (n + DPB - 1) >> DSHIFT;
    const int chunk = (((ne + NBLK - 1) / NBLK) + 3) & ~3;   // multiple of 4

    // workspace layout (16B-aligned blocks)
    char* ws = (char*)d_ws;
    size_t off = 0;
    float4* fwpre   = (float4*)(ws + off); off += (size_t)BB * NWIRE * 16;
    float4* swpre   = (float4*)(ws + off); off += (size_t)BB * NWIRE * 16;
    float4* srcdat4 = (float4*)(ws + off); off += (size_t)n * 32;
    float4* dstdat4 = (float4*)(ws + off); off += (size_t)n * 16;
    int*    bh      = (int*)(ws + off);    off += (size_t)nb * NBLK * 4;
    int*    btot    = (int*)(ws + off);    off += ((size_t)nb * 4 + 15) & ~15ull;
    int*    bbase   = (int*)(ws + off);    off += ((size_t)(nb + 1) * 4 + 15) & ~15ull;
    int2*   recs    = (int2*)(ws + off);   off += (size_t)ne * 8;

    hipLaunchKernelGGL(k_wires, dim3((BB * NWIRE + BS - 1) / BS), dim3(BS), 0, stream,
                       first_wires, second_wires, W, att_src, att_dst, w_mlp, fwpre, swpre);
    hipLaunchKernelGGL(k_nodes, dim3((n + BS - 1) / BS), dim3(BS), 0, stream,
                       indices, crossings, bbox, W, att_src, att_dst, w_mlp,
                       fwpre, swpre, srcdat4, dstdat4, n);
    hipLaunchKernelGGL(k_binA1, dim3(NBLK), dim3(BS), 0, stream,
                       edge_index, ne, nb, chunk, bh);
    hipLaunchKernelGGL(k_scanBlk, dim3((nb + 63) / 64), dim3(64), 0, stream,
                       bh, btot, nb);
    hipLaunchKernelGGL(k_scanBuck, dim3(1), dim3(1024), 0, stream,
                       btot, bbase, nb, ne);
    hipLaunchKernelGGL(k_binA2, dim3(NBLK), dim3(BS), 0, stream,
                       edge_index, edge_attr, W_e, att_edge, bh, bbase, ne, nb, chunk, recs);
    hipLaunchKernelGGL(k_gatB, dim3(nb), dim3(BS), 0, stream,
                       recs, bbase, srcdat4, dstdat4, bias, w_mlp, b_mlp, out, n);
}

// Round 12
// 249.136 us; speedup vs baseline: 1.0616x; 1.0353x over previous
//
#include <hip/hip_runtime.h>
#include <math.h>

#define BB 4
#define NWIRE 1536
#define NFEAT 16
#define BS 256
#define NBLK 256         // blocks for A1/A2 binning passes
#define DSHIFT 8         // 256 dsts per coarse bucket
#define DPB (1 << DSHIFT)
#define MAXNB 2048       // max buckets: supports n <= 524288 (src packed in 19 bits)

// ---- K1: per-wire scalar precompute ---------------------------------------
__global__ void k_wires(const float* __restrict__ fw, const float* __restrict__ sw,
                        const float* __restrict__ W, const float* __restrict__ att_src,
                        const float* __restrict__ att_dst, const float* __restrict__ wmlp,
                        float4* __restrict__ fwpre, float4* __restrict__ swpre) {
    int t = blockIdx.x * blockDim.x + threadIdx.x;
    if (t >= BB * NWIRE) return;
    const float* fp = fw + (size_t)t * NFEAT;
    const float* sp = sw + (size_t)t * NFEAT;
    float hf[4] = {0, 0, 0, 0}, hs[4] = {0, 0, 0, 0};
    #pragma unroll
    for (int k = 0; k < NFEAT; ++k) {
        float a = fp[k], b = sp[k];
        #pragma unroll
        for (int c = 0; c < 4; ++c) {
            hf[c] = fmaf(a, W[k * 4 + c], hf[c]);
            hs[c] = fmaf(b, W[(NFEAT + k) * 4 + c], hs[c]);
        }
    }
    float fs = 0, fd = 0, fq = 0, ss = 0, sd = 0, sq = 0;
    #pragma unroll
    for (int c = 0; c < 4; ++c) {
        float as = att_src[c], ad = att_dst[c], wm = wmlp[c];
        fs = fmaf(hf[c], as, fs); fd = fmaf(hf[c], ad, fd); fq = fmaf(hf[c], wm, fq);
        ss = fmaf(hs[c], as, ss); sd = fmaf(hs[c], ad, sd); sq = fmaf(hs[c], wm, sq);
    }
    fwpre[t] = make_float4(fs, fd, fq, 0.0f);
    swpre[t] = make_float4(ss, sd, sq, 0.0f);
}

// ---- K2: per-node scalars, PER-BATCH layout:
//      srcb[b*n+i] = float2(ps_b, q_b)   (3.2 MB per batch)
//      dstb[b*n+i] = pd_b
__global__ void k_nodes(const int* __restrict__ indices, const float* __restrict__ crossings,
                        const float* __restrict__ bbox, const float* __restrict__ W,
                        const float* __restrict__ att_src, const float* __restrict__ att_dst,
                        const float* __restrict__ wmlp,
                        const float4* __restrict__ fwpre, const float4* __restrict__ swpre,
                        float2* __restrict__ srcb, float* __restrict__ dstb, int n) {
    int i = blockIdx.x * blockDim.x + threadIdx.x;
    if (i >= n) return;
    float inv = rsqrtf(bbox[0] * bbox[0] + bbox[1] * bbox[1] + bbox[2] * bbox[2]);
    int2 idx = ((const int2*)indices)[i];
    float2 xc = ((const float2*)crossings)[i];
    int i0 = idx.x, i1 = idx.y;
    float x0 = xc.x * inv, x1 = xc.y * inv;
    float xs = 0, xd = 0, xq = 0;
    #pragma unroll
    for (int c = 0; c < 4; ++c) {
        float hc = fmaf(x0, W[32 * 4 + c], x1 * W[33 * 4 + c]);
        xs = fmaf(hc, att_src[c], xs);
        xd = fmaf(hc, att_dst[c], xd);
        xq = fmaf(hc, wmlp[c], xq);
    }
    #pragma unroll
    for (int b = 0; b < BB; ++b) {
        float4 f = fwpre[b * NWIRE + i0];
        float4 s = swpre[b * NWIRE + i1];
        srcb[(size_t)b * n + i] = make_float2(f.x + s.x + xs, f.z + s.z + xq);
        dstb[(size_t)b * n + i] = f.y + s.y + xd;
    }
}

// ---- A1: per-block coarse-bucket histogram (LDS only) ----------------------
// bh layout: [block][bucket] (row-contiguous per block)
__global__ void k_binA1(const int* __restrict__ ei, int ne, int nb, int chunk,
                        int* __restrict__ bh) {
    __shared__ int lc[MAXNB];
    for (int i = threadIdx.x; i < nb; i += BS) lc[i] = 0;
    __syncthreads();
    int blk = blockIdx.x;
    const int* dstp = ei + ne;
    int e0 = blk * chunk, e1 = min(e0 + chunk, ne);
    int e = e0 + threadIdx.x * 4;
    for (; e + 3 < e1; e += BS * 4) {
        int4 d4 = *(const int4*)(dstp + e);
        atomicAdd(&lc[d4.x >> DSHIFT], 1);
        atomicAdd(&lc[d4.y >> DSHIFT], 1);
        atomicAdd(&lc[d4.z >> DSHIFT], 1);
        atomicAdd(&lc[d4.w >> DSHIFT], 1);
    }
    for (; e < e1; e += BS * 4) {
        int ke = min(e + 4, e1);
        for (int k = e; k < ke; ++k) atomicAdd(&lc[dstp[k] >> DSHIFT], 1);
    }
    __syncthreads();
    int* row = bh + (size_t)blk * nb;
    for (int b = threadIdx.x; b < nb; b += BS) row[b] = lc[b];
}

// ---- S1: per-bucket exclusive scan over blocks (coalesced, 8-deep loads) ---
__global__ void k_scanBlk(int* __restrict__ bh, int* __restrict__ btot, int nb) {
    int b = blockIdx.x * blockDim.x + threadIdx.x;
    if (b >= nb) return;
    int run = 0;
    for (int k0 = 0; k0 < NBLK; k0 += 8) {
        int v[8];
        #pragma unroll
        for (int j = 0; j < 8; ++j) v[j] = bh[(size_t)(k0 + j) * nb + b];
        #pragma unroll
        for (int j = 0; j < 8; ++j) {
            int t = v[j];
            bh[(size_t)(k0 + j) * nb + b] = run;
            run += t;
        }
    }
    btot[b] = run;
}

// ---- S2: exclusive scan of bucket totals (1024 thr x 2 elems) --------------
__global__ void k_scanBuck(const int* __restrict__ btot, int* __restrict__ bbase,
                           int nb, int ne) {
    __shared__ int sh[1024];
    int t = threadIdx.x;
    int i0 = 2 * t, i1 = 2 * t + 1;
    int a = (i0 < nb) ? btot[i0] : 0;
    int b = (i1 < nb) ? btot[i1] : 0;
    sh[t] = a + b;
    __syncthreads();
    for (int ofs = 1; ofs < 1024; ofs <<= 1) {
        int u = (t >= ofs) ? sh[t - ofs] : 0;
        __syncthreads();
        sh[t] += u;
        __syncthreads();
    }
    int excl = sh[t] - (a + b);
    if (i0 < nb) bbase[i0] = excl;
    if (i1 < nb) bbase[i1] = excl + a;
    if (t == 0) bbase[nb] = ne;
}

// ---- A2: compute a_e, place records in (block,bucket) private sub-ranges ---
// record: x = (d & (DPB-1)) << 19 | src,  y = float bits of a_e
__global__ void k_binA2(const int* __restrict__ ei, const float* __restrict__ eattr,
                        const float* __restrict__ We, const float* __restrict__ att_edge,
                        const int* __restrict__ bh, const int* __restrict__ bbase,
                        int ne, int nb, int chunk, int2* __restrict__ recs) {
    __shared__ int curs[MAXNB];
    int blk = blockIdx.x;
    const int* row = bh + (size_t)blk * nb;
    for (int b = threadIdx.x; b < nb; b += BS)
        curs[b] = bbase[b] + row[b];
    __syncthreads();
    float v0 = fmaf(We[0], att_edge[0], fmaf(We[1], att_edge[1], fmaf(We[2], att_edge[2], We[3] * att_edge[3])));
    float v1 = fmaf(We[4], att_edge[0], fmaf(We[5], att_edge[1], fmaf(We[6], att_edge[2], We[7] * att_edge[3])));
    float v2 = fmaf(We[8], att_edge[0], fmaf(We[9], att_edge[1], fmaf(We[10], att_edge[2], We[11] * att_edge[3])));
    float v3 = fmaf(We[12], att_edge[0], fmaf(We[13], att_edge[1], fmaf(We[14], att_edge[2], We[15] * att_edge[3])));
    const int* srcp = ei;
    const int* dstp = ei + ne;
    const float4* ea4 = (const float4*)eattr;
    int e0 = blk * chunk, e1 = min(e0 + chunk, ne);
    int e = e0 + threadIdx.x * 4;
    for (; e + 3 < e1; e += BS * 4) {
        int4 s4 = *(const int4*)(srcp + e);
        int4 d4 = *(const int4*)(dstp + e);
        float4 a0 = ea4[e], a1 = ea4[e + 1], a2 = ea4[e + 2], a3 = ea4[e + 3];
        float ae0 = fmaf(a0.x, v0, fmaf(a0.y, v1, fmaf(a0.z, v2, a0.w * v3)));
        float ae1 = fmaf(a1.x, v0, fmaf(a1.y, v1, fmaf(a1.z, v2, a1.w * v3)));
        float ae2 = fmaf(a2.x, v0, fmaf(a2.y, v1, fmaf(a2.z, v2, a2.w * v3)));
        float ae3 = fmaf(a3.x, v0, fmaf(a3.y, v1, fmaf(a3.z, v2, a3.w * v3)));
        int p0 = atomicAdd(&curs[d4.x >> DSHIFT], 1);
        int p1 = atomicAdd(&curs[d4.y >> DSHIFT], 1);
        int p2 = atomicAdd(&curs[d4.z >> DSHIFT], 1);
        int p3 = atomicAdd(&curs[d4.w >> DSHIFT], 1);
        recs[p0] = make_int2(((d4.x & (DPB - 1)) << 19) | s4.x, __float_as_int(ae0));
        recs[p1] = make_int2(((d4.y & (DPB - 1)) << 19) | s4.y, __float_as_int(ae1));
        recs[p2] = make_int2(((d4.z & (DPB - 1)) << 19) | s4.z, __float_as_int(ae2));
        recs[p3] = make_int2(((d4.w & (DPB - 1)) << 19) | s4.w, __float_as_int(ae3));
    }
    for (; e < e1; e += BS * 4) {
        int ke = min(e + 4, e1);
        for (int k = e; k < ke; ++k) {
            int s = srcp[k], d = dstp[k];
            float4 ea = ea4[k];
            float ae = fmaf(ea.x, v0, fmaf(ea.y, v1, fmaf(ea.z, v2, ea.w * v3)));
            int pos = atomicAdd(&curs[d >> DSHIFT], 1);
            recs[pos] = make_int2(((d & (DPB - 1)) << 19) | s, __float_as_int(ae));
        }
    }
}

// ---- GB: per-(bucket,batch) GAT. XCD-swizzled: batch b -> XCDs {2b,2b+1} ---
__global__ void __launch_bounds__(BS)
k_gatB(const int2* __restrict__ recs, const int* __restrict__ bbase,
       const float2* __restrict__ srcb, const float* __restrict__ dstb,
       const float* __restrict__ bias, const float* __restrict__ wmlp,
       const float* __restrict__ bmlp, float* __restrict__ out, int n, int nb) {
    __shared__ float2 acc[DPB];   // per dst: (den, num)
    __shared__ float pds[DPB];
    int g = blockIdx.x;
    int s = g & 7;
    int batch = s >> 1;
    int bucket = (g >> 3) * 2 + (s & 1);
    if (bucket >= nb) return;
    int r0 = bbase[bucket], r1 = bbase[bucket + 1];
    int dbase = bucket << DSHIFT;
    int dmax = min(DPB, n - dbase);
    const float* db = dstb + (size_t)batch * n;
    for (int i = threadIdx.x; i < DPB; i += BS) acc[i] = make_float2(0.0f, 0.0f);
    for (int i = threadIdx.x; i < dmax; i += BS) pds[i] = db[dbase + i];
    __syncthreads();
    const float2* sb = srcb + (size_t)batch * n;
    int i = r0 + threadIdx.x;
    for (; i + 3 * BS < r1; i += 4 * BS) {
        int2 ra = recs[i], rb = recs[i + BS], rc = recs[i + 2 * BS], rd = recs[i + 3 * BS];
        float2 pa = sb[ra.x & 0x7FFFF];
        float2 pb = sb[rb.x & 0x7FFFF];
        float2 pc = sb[rc.x & 0x7FFFF];
        float2 pd = sb[rd.x & 0x7FFFF];
        float lg, ex;
        int dlo;
        dlo = (unsigned)ra.x >> 19;
        lg = pa.x + pds[dlo] + __int_as_float(ra.y); lg = lg > 0.0f ? lg : 0.2f * lg; ex = expf(lg);
        atomicAdd(&acc[dlo].x, ex); atomicAdd(&acc[dlo].y, ex * pa.y);
        dlo = (unsigned)rb.x >> 19;
        lg = pb.x + pds[dlo] + __int_as_float(rb.y); lg = lg > 0.0f ? lg : 0.2f * lg; ex = expf(lg);
        atomicAdd(&acc[dlo].x, ex); atomicAdd(&acc[dlo].y, ex * pb.y);
        dlo = (unsigned)rc.x >> 19;
        lg = pc.x + pds[dlo] + __int_as_float(rc.y); lg = lg > 0.0f ? lg : 0.2f * lg; ex = expf(lg);
        atomicAdd(&acc[dlo].x, ex); atomicAdd(&acc[dlo].y, ex * pc.y);
        dlo = (unsigned)rd.x >> 19;
        lg = pd.x + pds[dlo] + __int_as_float(rd.y); lg = lg > 0.0f ? lg : 0.2f * lg; ex = expf(lg);
        atomicAdd(&acc[dlo].x, ex); atomicAdd(&acc[dlo].y, ex * pd.y);
    }
    for (; i < r1; i += BS) {
        int2 r = recs[i];
        float2 pq = sb[r.x & 0x7FFFF];
        int dlo = (unsigned)r.x >> 19;
        float lg = pq.x + pds[dlo] + __int_as_float(r.y);
        lg = lg > 0.0f ? lg : 0.2f * lg;
        float ex = expf(lg);
        atomicAdd(&acc[dlo].x, ex); atomicAdd(&acc[dlo].y, ex * pq.y);
    }
    __syncthreads();
    float cst = fmaf(bias[0], wmlp[0], fmaf(bias[1], wmlp[1], fmaf(bias[2], wmlp[2], bias[3] * wmlp[3]))) + bmlp[0];
    float* ob = out + (size_t)batch * n;
    for (int i2 = threadIdx.x; i2 < dmax; i2 += BS)
        ob[dbase + i2] = acc[i2].y / (acc[i2].x + 1e-16f) + cst;
}

extern "C" void kernel_launch(void* const* d_in, const int* in_sizes, int n_in,
                              void* d_out, int out_size, void* d_ws, size_t ws_size,
                              hipStream_t stream) {
    const float* first_wires  = (const float*)d_in[0];
    const float* second_wires = (const float*)d_in[1];
    const float* crossings    = (const float*)d_in[2];
    const float* bbox         = (const float*)d_in[3];
    const float* edge_attr    = (const float*)d_in[4];
    const int*   indices      = (const int*)d_in[5];
    const int*   edge_index   = (const int*)d_in[6];
    const float* W            = (const float*)d_in[7];
    const float* att_src      = (const float*)d_in[8];
    const float* att_dst      = (const float*)d_in[9];
    const float* W_e          = (const float*)d_in[10];
    const float* att_edge     = (const float*)d_in[11];
    const float* bias         = (const float*)d_in[12];
    const float* w_mlp        = (const float*)d_in[13];
    const float* b_mlp        = (const float*)d_in[14];
    float* out = (float*)d_out;

    const int n  = in_sizes[5] / 2;   // N_CROSS (must be < 524288 for packing)
    const int ne = in_sizes[6] / 2;   // N_EDGES
    const int nb = (n + DPB - 1) >> DSHIFT;
    const int nbp = (nb + 1) & ~1;                           // padded to even
    const int chunk = (((ne + NBLK - 1) / NBLK) + 3) & ~3;   // multiple of 4

    // workspace layout (16B-aligned blocks)
    char* ws = (char*)d_ws;
    size_t off = 0;
    float4* fwpre = (float4*)(ws + off); off += (size_t)BB * NWIRE * 16;
    float4* swpre = (float4*)(ws + off); off += (size_t)BB * NWIRE * 16;
    float2* srcb  = (float2*)(ws + off); off += (size_t)BB * n * 8;
    float*  dstb  = (float*)(ws + off);  off += (size_t)BB * n * 4;
    int*    bh    = (int*)(ws + off);    off += (size_t)nb * NBLK * 4;
    int*    btot  = (int*)(ws + off);    off += ((size_t)nb * 4 + 15) & ~15ull;
    int*    bbase = (int*)(ws + off);    off += ((size_t)(nb + 1) * 4 + 15) & ~15ull;
    int2*   recs  = (int2*)(ws + off);   off += (size_t)ne * 8;

    hipLaunchKernelGGL(k_wires, dim3((BB * NWIRE + BS - 1) / BS), dim3(BS), 0, stream,
                       first_wires, second_wires, W, att_src, att_dst, w_mlp, fwpre, swpre);
    hipLaunchKernelGGL(k_nodes, dim3((n + BS - 1) / BS), dim3(BS), 0, stream,
                       indices, crossings, bbox, W, att_src, att_dst, w_mlp,
                       fwpre, swpre, srcb, dstb, n);
    hipLaunchKernelGGL(k_binA1, dim3(NBLK), dim3(BS), 0, stream,
                       edge_index, ne, nb, chunk, bh);
    hipLaunchKernelGGL(k_scanBlk, dim3((nb + 63) / 64), dim3(64), 0, stream,
                       bh, btot, nb);
    hipLaunchKernelGGL(k_scanBuck, dim3(1), dim3(1024), 0, stream,
                       btot, bbase, nb, ne);
    hipLaunchKernelGGL(k_binA2, dim3(NBLK), dim3(BS), 0, stream,
                       edge_index, edge_attr, W_e, att_edge, bh, bbase, ne, nb, chunk, recs);
    hipLaunchKernelGGL(k_gatB, dim3(nbp * 4), dim3(BS), 0, stream,
                       recs, bbase, srcb, dstb, bias, w_mlp, b_mlp, out, n, nb);
}

// Round 16
// 234.463 us; speedup vs baseline: 1.1280x; 1.0626x over previous
//
#include <hip/hip_runtime.h>
#include <math.h>

#define BB 4
#define NWIRE 1536
#define NFEAT 16
#define BS 256
#define NBLK 256         // blocks for A1/A2 binning passes
#define DSHIFT 8         // 256 dsts per coarse bucket
#define DPB (1 << DSHIFT)
#define MAXNB 2048       // max buckets: supports n <= 524288 (src packed in 19 bits)

// ---- K1: per-wire scalar precompute ---------------------------------------
__global__ void k_wires(const float* __restrict__ fw, const float* __restrict__ sw,
                        const float* __restrict__ W, const float* __restrict__ att_src,
                        const float* __restrict__ att_dst, const float* __restrict__ wmlp,
                        float4* __restrict__ fwpre, float4* __restrict__ swpre) {
    int t = blockIdx.x * blockDim.x + threadIdx.x;
    if (t >= BB * NWIRE) return;
    const float* fp = fw + (size_t)t * NFEAT;
    const float* sp = sw + (size_t)t * NFEAT;
    float hf[4] = {0, 0, 0, 0}, hs[4] = {0, 0, 0, 0};
    #pragma unroll
    for (int k = 0; k < NFEAT; ++k) {
        float a = fp[k], b = sp[k];
        #pragma unroll
        for (int c = 0; c < 4; ++c) {
            hf[c] = fmaf(a, W[k * 4 + c], hf[c]);
            hs[c] = fmaf(b, W[(NFEAT + k) * 4 + c], hs[c]);
        }
    }
    float fs = 0, fd = 0, fq = 0, ss = 0, sd = 0, sq = 0;
    #pragma unroll
    for (int c = 0; c < 4; ++c) {
        float as = att_src[c], ad = att_dst[c], wm = wmlp[c];
        fs = fmaf(hf[c], as, fs); fd = fmaf(hf[c], ad, fd); fq = fmaf(hf[c], wm, fq);
        ss = fmaf(hs[c], as, ss); sd = fmaf(hs[c], ad, sd); sq = fmaf(hs[c], wm, sq);
    }
    fwpre[t] = make_float4(fs, fd, fq, 0.0f);
    swpre[t] = make_float4(ss, sd, sq, 0.0f);
}

// ---- K2: per-node scalars, PER-BATCH layout:
//      srcb[b*n+i] = float2(ps_b, q_b)   (3.2 MB per batch)
//      dstb[b*n+i] = pd_b
__global__ void k_nodes(const int* __restrict__ indices, const float* __restrict__ crossings,
                        const float* __restrict__ bbox, const float* __restrict__ W,
                        const float* __restrict__ att_src, const float* __restrict__ att_dst,
                        const float* __restrict__ wmlp,
                        const float4* __restrict__ fwpre, const float4* __restrict__ swpre,
                        float2* __restrict__ srcb, float* __restrict__ dstb, int n) {
    int i = blockIdx.x * blockDim.x + threadIdx.x;
    if (i >= n) return;
    float inv = rsqrtf(bbox[0] * bbox[0] + bbox[1] * bbox[1] + bbox[2] * bbox[2]);
    int2 idx = ((const int2*)indices)[i];
    float2 xc = ((const float2*)crossings)[i];
    int i0 = idx.x, i1 = idx.y;
    float x0 = xc.x * inv, x1 = xc.y * inv;
    float xs = 0, xd = 0, xq = 0;
    #pragma unroll
    for (int c = 0; c < 4; ++c) {
        float hc = fmaf(x0, W[32 * 4 + c], x1 * W[33 * 4 + c]);
        xs = fmaf(hc, att_src[c], xs);
        xd = fmaf(hc, att_dst[c], xd);
        xq = fmaf(hc, wmlp[c], xq);
    }
    #pragma unroll
    for (int b = 0; b < BB; ++b) {
        float4 f = fwpre[b * NWIRE + i0];
        float4 s = swpre[b * NWIRE + i1];
        srcb[(size_t)b * n + i] = make_float2(f.x + s.x + xs, f.z + s.z + xq);
        dstb[(size_t)b * n + i] = f.y + s.y + xd;
    }
}

// ---- A1: per-block coarse-bucket histogram (LDS only) ----------------------
// bh layout: [block][bucket] (row-contiguous per block)
__global__ void k_binA1(const int* __restrict__ ei, int ne, int nb, int chunk,
                        int* __restrict__ bh) {
    __shared__ int lc[MAXNB];
    for (int i = threadIdx.x; i < nb; i += BS) lc[i] = 0;
    __syncthreads();
    int blk = blockIdx.x;
    const int* dstp = ei + ne;
    int e0 = blk * chunk, e1 = min(e0 + chunk, ne);
    int e = e0 + threadIdx.x * 4;
    for (; e + 3 < e1; e += BS * 4) {
        int4 d4 = *(const int4*)(dstp + e);
        atomicAdd(&lc[d4.x >> DSHIFT], 1);
        atomicAdd(&lc[d4.y >> DSHIFT], 1);
        atomicAdd(&lc[d4.z >> DSHIFT], 1);
        atomicAdd(&lc[d4.w >> DSHIFT], 1);
    }
    for (; e < e1; e += BS * 4) {
        int ke = min(e + 4, e1);
        for (int k = e; k < ke; ++k) atomicAdd(&lc[dstp[k] >> DSHIFT], 1);
    }
    __syncthreads();
    int* row = bh + (size_t)blk * nb;
    for (int b = threadIdx.x; b < nb; b += BS) row[b] = lc[b];
}

// ---- S1: per-bucket exclusive scan over blocks (coalesced, 8-deep loads) ---
__global__ void k_scanBlk(int* __restrict__ bh, int* __restrict__ btot, int nb) {
    int b = blockIdx.x * blockDim.x + threadIdx.x;
    if (b >= nb) return;
    int run = 0;
    for (int k0 = 0; k0 < NBLK; k0 += 8) {
        int v[8];
        #pragma unroll
        for (int j = 0; j < 8; ++j) v[j] = bh[(size_t)(k0 + j) * nb + b];
        #pragma unroll
        for (int j = 0; j < 8; ++j) {
            int t = v[j];
            bh[(size_t)(k0 + j) * nb + b] = run;
            run += t;
        }
    }
    btot[b] = run;
}

// ---- S2: exclusive scan of bucket totals (1024 thr x 2 elems) --------------
__global__ void k_scanBuck(const int* __restrict__ btot, int* __restrict__ bbase,
                           int* __restrict__ start, int nb, int n, int ne) {
    __shared__ int sh[1024];
    int t = threadIdx.x;
    int i0 = 2 * t, i1 = 2 * t + 1;
    int a = (i0 < nb) ? btot[i0] : 0;
    int b = (i1 < nb) ? btot[i1] : 0;
    sh[t] = a + b;
    __syncthreads();
    for (int ofs = 1; ofs < 1024; ofs <<= 1) {
        int u = (t >= ofs) ? sh[t - ofs] : 0;
        __syncthreads();
        sh[t] += u;
        __syncthreads();
    }
    int excl = sh[t] - (a + b);
    if (i0 < nb) bbase[i0] = excl;
    if (i1 < nb) bbase[i1] = excl + a;
    if (t == 0) { bbase[nb] = ne; start[n] = ne; }
}

// ---- A2: compute a_e, place records in (block,bucket) private sub-ranges ---
// record: x = (d & (DPB-1)) << 19 | src,  y = float bits of a_e
__global__ void k_binA2(const int* __restrict__ ei, const float* __restrict__ eattr,
                        const float* __restrict__ We, const float* __restrict__ att_edge,
                        const int* __restrict__ bh, const int* __restrict__ bbase,
                        int ne, int nb, int chunk, int2* __restrict__ recs) {
    __shared__ int curs[MAXNB];
    int blk = blockIdx.x;
    const int* row = bh + (size_t)blk * nb;
    for (int b = threadIdx.x; b < nb; b += BS)
        curs[b] = bbase[b] + row[b];
    __syncthreads();
    float v0 = fmaf(We[0], att_edge[0], fmaf(We[1], att_edge[1], fmaf(We[2], att_edge[2], We[3] * att_edge[3])));
    float v1 = fmaf(We[4], att_edge[0], fmaf(We[5], att_edge[1], fmaf(We[6], att_edge[2], We[7] * att_edge[3])));
    float v2 = fmaf(We[8], att_edge[0], fmaf(We[9], att_edge[1], fmaf(We[10], att_edge[2], We[11] * att_edge[3])));
    float v3 = fmaf(We[12], att_edge[0], fmaf(We[13], att_edge[1], fmaf(We[14], att_edge[2], We[15] * att_edge[3])));
    const int* srcp = ei;
    const int* dstp = ei + ne;
    const float4* ea4 = (const float4*)eattr;
    int e0 = blk * chunk, e1 = min(e0 + chunk, ne);
    int e = e0 + threadIdx.x * 4;
    for (; e + 3 < e1; e += BS * 4) {
        int4 s4 = *(const int4*)(srcp + e);
        int4 d4 = *(const int4*)(dstp + e);
        float4 a0 = ea4[e], a1 = ea4[e + 1], a2 = ea4[e + 2], a3 = ea4[e + 3];
        float ae0 = fmaf(a0.x, v0, fmaf(a0.y, v1, fmaf(a0.z, v2, a0.w * v3)));
        float ae1 = fmaf(a1.x, v0, fmaf(a1.y, v1, fmaf(a1.z, v2, a1.w * v3)));
        float ae2 = fmaf(a2.x, v0, fmaf(a2.y, v1, fmaf(a2.z, v2, a2.w * v3)));
        float ae3 = fmaf(a3.x, v0, fmaf(a3.y, v1, fmaf(a3.z, v2, a3.w * v3)));
        int p0 = atomicAdd(&curs[d4.x >> DSHIFT], 1);
        int p1 = atomicAdd(&curs[d4.y >> DSHIFT], 1);
        int p2 = atomicAdd(&curs[d4.z >> DSHIFT], 1);
        int p3 = atomicAdd(&curs[d4.w >> DSHIFT], 1);
        recs[p0] = make_int2(((d4.x & (DPB - 1)) << 19) | s4.x, __float_as_int(ae0));
        recs[p1] = make_int2(((d4.y & (DPB - 1)) << 19) | s4.y, __float_as_int(ae1));
        recs[p2] = make_int2(((d4.z & (DPB - 1)) << 19) | s4.z, __float_as_int(ae2));
        recs[p3] = make_int2(((d4.w & (DPB - 1)) << 19) | s4.w, __float_as_int(ae3));
    }
    for (; e < e1; e += BS * 4) {
        int ke = min(e + 4, e1);
        for (int k = e; k < ke; ++k) {
            int s = srcp[k], d = dstp[k];
            float4 ea = ea4[k];
            float ae = fmaf(ea.x, v0, fmaf(ea.y, v1, fmaf(ea.z, v2, ea.w * v3)));
            int pos = atomicAdd(&curs[d >> DSHIFT], 1);
            recs[pos] = make_int2(((d & (DPB - 1)) << 19) | s, __float_as_int(ae));
        }
    }
}

// ---- B: per-bucket refine -> dst-sorted csr + exact start[] (int LDS only) -
__global__ void __launch_bounds__(BS)
k_binB(const int2* __restrict__ recs, const int* __restrict__ bbase,
       int2* __restrict__ csr, int* __restrict__ start, int n, int nb) {
    __shared__ int cnt[DPB];
    __shared__ int tsum[BS];
    int b = blockIdx.x;
    int r0 = bbase[b], r1 = bbase[b + 1];
    int nrec = r1 - r0;
    cnt[threadIdx.x] = 0;            // DPB == BS
    __syncthreads();
    for (int i = threadIdx.x; i < nrec; i += BS)
        atomicAdd(&cnt[(unsigned)recs[r0 + i].x >> 19], 1);
    __syncthreads();
    int c = cnt[threadIdx.x];
    tsum[threadIdx.x] = c;
    __syncthreads();
    for (int ofs = 1; ofs < BS; ofs <<= 1) {
        int u = (threadIdx.x >= ofs) ? tsum[threadIdx.x - ofs] : 0;
        __syncthreads();
        tsum[threadIdx.x] += u;
        __syncthreads();
    }
    int excl = tsum[threadIdx.x] - c;
    int d = (b << DSHIFT) + threadIdx.x;
    if (d < n) start[d] = r0 + excl;
    cnt[threadIdx.x] = excl;         // reuse as cursor
    __syncthreads();
    for (int i = threadIdx.x; i < nrec; i += BS) {
        int2 r = recs[r0 + i];
        int dlo = (unsigned)r.x >> 19;
        int pos = r0 + atomicAdd(&cnt[dlo], 1);
        csr[pos] = make_int2(r.x & 0x7FFFF, r.y);
    }
}

// ---- G: per-(dst,batch) GAT over CSR — no atomics, coalesced csr reads -----
// XCD swizzle: batch = (blockIdx&7)>>1 so each XCD pair sees one batch's srcb
__global__ void __launch_bounds__(BS)
k_gat(const int2* __restrict__ csr, const int* __restrict__ start,
      const float2* __restrict__ srcb, const float* __restrict__ dstb,
      const float* __restrict__ bias, const float* __restrict__ wmlp,
      const float* __restrict__ bmlp, float* __restrict__ out, int n, int nb) {
    int g = blockIdx.x;
    int s = g & 7;
    int batch = s >> 1;
    int dblk = (g >> 3) * 2 + (s & 1);
    if (dblk >= nb) return;
    int d = (dblk << DSHIFT) + threadIdx.x;
    if (d >= n) return;
    int st = start[d], en = start[d + 1];
    const float2* sb = srcb + (size_t)batch * n;
    float pd = dstb[(size_t)batch * n + d];
    float den = 0.0f, num = 0.0f;
    int j = st;
    for (; j + 4 <= en; j += 4) {
        int2 r0 = csr[j], r1 = csr[j + 1], r2 = csr[j + 2], r3 = csr[j + 3];
        float2 p0 = sb[r0.x];
        float2 p1 = sb[r1.x];
        float2 p2 = sb[r2.x];
        float2 p3 = sb[r3.x];
        float lg, ex;
        lg = p0.x + pd + __int_as_float(r0.y); lg = lg > 0.0f ? lg : 0.2f * lg;
        ex = expf(lg); den += ex; num = fmaf(ex, p0.y, num);
        lg = p1.x + pd + __int_as_float(r1.y); lg = lg > 0.0f ? lg : 0.2f * lg;
        ex = expf(lg); den += ex; num = fmaf(ex, p1.y, num);
        lg = p2.x + pd + __int_as_float(r2.y); lg = lg > 0.0f ? lg : 0.2f * lg;
        ex = expf(lg); den += ex; num = fmaf(ex, p2.y, num);
        lg = p3.x + pd + __int_as_float(r3.y); lg = lg > 0.0f ? lg : 0.2f * lg;
        ex = expf(lg); den += ex; num = fmaf(ex, p3.y, num);
    }
    for (; j < en; ++j) {
        int2 r = csr[j];
        float2 pq = sb[r.x];
        float lg = pq.x + pd + __int_as_float(r.y);
        lg = lg > 0.0f ? lg : 0.2f * lg;
        float ex = expf(lg);
        den += ex; num = fmaf(ex, pq.y, num);
    }
    float cst = fmaf(bias[0], wmlp[0], fmaf(bias[1], wmlp[1], fmaf(bias[2], wmlp[2], bias[3] * wmlp[3]))) + bmlp[0];
    out[(size_t)batch * n + d] = num / (den + 1e-16f) + cst;
}

extern "C" void kernel_launch(void* const* d_in, const int* in_sizes, int n_in,
                              void* d_out, int out_size, void* d_ws, size_t ws_size,
                              hipStream_t stream) {
    const float* first_wires  = (const float*)d_in[0];
    const float* second_wires = (const float*)d_in[1];
    const float* crossings    = (const float*)d_in[2];
    const float* bbox         = (const float*)d_in[3];
    const float* edge_attr    = (const float*)d_in[4];
    const int*   indices      = (const int*)d_in[5];
    const int*   edge_index   = (const int*)d_in[6];
    const float* W            = (const float*)d_in[7];
    const float* att_src      = (const float*)d_in[8];
    const float* att_dst      = (const float*)d_in[9];
    const float* W_e          = (const float*)d_in[10];
    const float* att_edge     = (const float*)d_in[11];
    const float* bias         = (const float*)d_in[12];
    const float* w_mlp        = (const float*)d_in[13];
    const float* b_mlp        = (const float*)d_in[14];
    float* out = (float*)d_out;

    const int n  = in_sizes[5] / 2;   // N_CROSS (must be < 524288 for packing)
    const int ne = in_sizes[6] / 2;   // N_EDGES
    const int nb = (n + DPB - 1) >> DSHIFT;
    const int nbp = (nb + 1) & ~1;                           // padded to even
    const int chunk = (((ne + NBLK - 1) / NBLK) + 3) & ~3;   // multiple of 4

    // workspace layout (16B-aligned blocks)
    char* ws = (char*)d_ws;
    size_t off = 0;
    float4* fwpre = (float4*)(ws + off); off += (size_t)BB * NWIRE * 16;
    float4* swpre = (float4*)(ws + off); off += (size_t)BB * NWIRE * 16;
    float2* srcb  = (float2*)(ws + off); off += (size_t)BB * n * 8;
    float*  dstb  = (float*)(ws + off);  off += (size_t)BB * n * 4;
    int*    bh    = (int*)(ws + off);    off += (size_t)nb * NBLK * 4;
    int*    btot  = (int*)(ws + off);    off += ((size_t)nb * 4 + 15) & ~15ull;
    int*    bbase = (int*)(ws + off);    off += ((size_t)(nb + 1) * 4 + 15) & ~15ull;
    int*    start = (int*)(ws + off);    off += ((size_t)(n + 1) * 4 + 15) & ~15ull;
    int2*   recs  = (int2*)(ws + off);   off += (size_t)ne * 8;
    int2*   csr   = (int2*)(ws + off);   off += (size_t)ne * 8;

    hipLaunchKernelGGL(k_wires, dim3((BB * NWIRE + BS - 1) / BS), dim3(BS), 0, stream,
                       first_wires, second_wires, W, att_src, att_dst, w_mlp, fwpre, swpre);
    hipLaunchKernelGGL(k_nodes, dim3((n + BS - 1) / BS), dim3(BS), 0, stream,
                       indices, crossings, bbox, W, att_src, att_dst, w_mlp,
                       fwpre, swpre, srcb, dstb, n);
    hipLaunchKernelGGL(k_binA1, dim3(NBLK), dim3(BS), 0, stream,
                       edge_index, ne, nb, chunk, bh);
    hipLaunchKernelGGL(k_scanBlk, dim3((nb + 63) / 64), dim3(64), 0, stream,
                       bh, btot, nb);
    hipLaunchKernelGGL(k_scanBuck, dim3(1), dim3(1024), 0, stream,
                       btot, bbase, start, nb, n, ne);
    hipLaunchKernelGGL(k_binA2, dim3(NBLK), dim3(BS), 0, stream,
                       edge_index, edge_attr, W_e, att_edge, bh, bbase, ne, nb, chunk, recs);
    hipLaunchKernelGGL(k_binB, dim3(nb), dim3(BS), 0, stream,
                       recs, bbase, csr, start, n, nb);
    hipLaunchKernelGGL(k_gat, dim3(nbp * 4), dim3(BS), 0, stream,
                       csr, start, srcb, dstb, bias, w_mlp, b_mlp, out, n, nb);
}